// Round 3
// baseline (67.199 us; speedup 1.0000x reference)
//
#include <hip/hip_runtime.h>

namespace {
constexpr int AH = 9, AW = 9, NS = AH * AW;   // 81 samples per ROI
constexpr int C = 256, H = 64, W = 64, HW = H * W;
constexpr float SCALE = 0.0625f;
constexpr int ELEMS = C * NS;                 // 20736 outputs per ROI
constexpr int CH = 64;                        // channels per chunk
constexpr int NXCD = 8;
}

// ---------- pass 0: bucket ROI indices by batch ----------
__global__ __launch_bounds__(256)
void build_lists_kernel(const float* __restrict__ rois, int R,
                        int* __restrict__ counts, int* __restrict__ lists)
{
    __shared__ int l_cnt[4];
    const int t = threadIdx.x;
    if (t < 4) l_cnt[t] = 0;
    __syncthreads();
    for (int r = t; r < R; r += 256) {
        const int b = (int)rois[r * 5];
        const int k = atomicAdd(&l_cnt[b], 1);
        lists[b * R + k] = r;
    }
    __syncthreads();
    if (t < 4) counts[t] = l_cnt[t];
}

// ---------- pass 1: NCHW -> NHWC transpose into workspace ----------
__global__ __launch_bounds__(256)
void nchw_to_nhwc_kernel(const float* __restrict__ in, float* __restrict__ out)
{
    __shared__ float tile[32][33];
    const int b  = blockIdx.z;
    const int p0 = blockIdx.x * 32;
    const int c0 = blockIdx.y * 32;
    const float* src = in  + (size_t)b * C * HW;
    float*       dst = out + (size_t)b * HW * C;
    const int tx = threadIdx.x;   // 0..31
    const int ty = threadIdx.y;   // 0..7
    #pragma unroll
    for (int k = 0; k < 4; ++k)
        tile[ty + 8 * k][tx] = src[(size_t)(c0 + ty + 8 * k) * HW + p0 + tx];
    __syncthreads();
    #pragma unroll
    for (int k = 0; k < 4; ++k)
        dst[(size_t)(p0 + ty + 8 * k) * C + c0 + tx] = tile[tx][ty + 8 * k];
}

// ---------- pass 2: ROI align from NHWC, batch->XCD affine ----------
// blockIdx -> xcd = blockIdx%8; batch = xcd>>1 (4 MB slab per batch = one L2)
__global__ __launch_bounds__(256)
void rod_align_nhwc_kernel(const float* __restrict__ nhwc,
                           const float* __restrict__ rois,
                           const int* __restrict__ counts,
                           const int* __restrict__ lists,
                           float* __restrict__ out, int R)
{
    __shared__ float4 s_w[NS];
    __shared__ int    s_off[NS];            // (y0*W + x0) * C
    __shared__ float  s_buf[NS][CH + 1];

    const int xcd  = blockIdx.x & (NXCD - 1);
    const int idx  = blockIdx.x >> 3;
    const int b    = xcd >> 1;              // batch for this XCD pair
    const int par  = xcd & 1;
    const int half = idx & 1;
    const int slot = idx >> 1;
    const int k    = slot * 2 + par;        // index within batch list
    if (k >= counts[b]) return;
    const int r = lists[b * R + k];

    const int t    = threadIdx.x;
    const int wave = t >> 6;
    const int lane = t & 63;

    const float* roi = rois + r * 5;
    const float x1 = roi[1] * SCALE;
    const float y1 = roi[2] * SCALE;
    const float x2 = roi[3] * SCALE;
    const float y2 = roi[4] * SCALE;
    const float bin_h = (y2 - y1) * 0.125f;
    const float bin_w = (x2 - x1) * 0.125f;

    if (t < NS) {
        const int i = t / AW;
        const int j = t - i * AW;
        const float Y = y1 + (float)i * bin_h;
        const float X = x1 + (float)j * bin_w;
        const bool valid = (Y >= 0.f) && (Y < (float)H) &&
                           (X >= 0.f) && (X < (float)W);
        const float fy = fminf(fmaxf(floorf(Y), 0.f), (float)(H - 2));
        const float fx = fminf(fmaxf(floorf(X), 0.f), (float)(W - 2));
        const float ly = Y - fy, lx = X - fx;
        const float hy = 1.f - ly, hx = 1.f - lx;
        const float v = valid ? 1.f : 0.f;
        s_off[t] = ((int)fy * W + (int)fx) * C;
        s_w[t] = make_float4(hy * hx * v, hy * lx * v, ly * hx * v, ly * lx * v);
    }
    __syncthreads();

    const float* __restrict__ fb = nhwc + (size_t)b * (HW * C);
    float* __restrict__ ob = out + (size_t)r * ELEMS;

    // per-wave contiguous sample range (row locality for L1)
    const int s_begin = wave * 21;
    const int s_end   = (s_begin + 21 < NS) ? s_begin + 21 : NS;

    for (int ci = 0; ci < 2; ++ci) {
        const int c0 = (half * 2 + ci) * CH;
        const float* __restrict__ fc = fb + c0 + lane;
        for (int s = s_begin; s < s_end; ++s) {
            const int off = s_off[s];
            const float4 w4 = s_w[s];
            const float v = fc[off]             * w4.x
                          + fc[off + C]         * w4.y
                          + fc[off + W * C]     * w4.z
                          + fc[off + W * C + C] * w4.w;
            s_buf[s][lane] = v;
        }
        __syncthreads();
        // contiguous 5184-float slab: out[r, c0+cc, ss], f = cc*81 + ss
        float* __restrict__ oc = ob + c0 * NS;
        for (int f = t; f < CH * NS; f += 256) {
            const int cc = f / NS;
            const int ss = f - cc * NS;
            __builtin_nontemporal_store(s_buf[ss][cc], &oc[f]);
        }
        __syncthreads();
    }
}

// ---------- fallback (round-1 kernel) if workspace too small / B != 4 ----------
__global__ __launch_bounds__(256, 8)
void rod_align_nchw_kernel(const float* __restrict__ feat,
                           const float* __restrict__ rois,
                           float* __restrict__ out)
{
    __shared__ float4 s_w[NS];
    __shared__ int    s_off[NS];

    const int r = blockIdx.x;
    const int t = threadIdx.x;

    const float* roi = rois + r * 5;
    const int   b  = (int)roi[0];
    const float x1 = roi[1] * SCALE;
    const float y1 = roi[2] * SCALE;
    const float x2 = roi[3] * SCALE;
    const float y2 = roi[4] * SCALE;
    const float bin_h = (y2 - y1) * 0.125f;
    const float bin_w = (x2 - x1) * 0.125f;

    if (t < NS) {
        const int i = t / AW;
        const int j = t - i * AW;
        const float Y = y1 + (float)i * bin_h;
        const float X = x1 + (float)j * bin_w;
        const bool valid = (Y >= 0.f) && (Y < (float)H) &&
                           (X >= 0.f) && (X < (float)W);
        const float fy = fminf(fmaxf(floorf(Y), 0.f), (float)(H - 2));
        const float fx = fminf(fmaxf(floorf(X), 0.f), (float)(W - 2));
        const float ly = Y - fy, lx = X - fx;
        const float hy = 1.f - ly, hx = 1.f - lx;
        const float v = valid ? 1.f : 0.f;
        s_off[t] = (int)fy * W + (int)fx;
        s_w[t] = make_float4(hy * hx * v, hy * lx * v, ly * hx * v, ly * lx * v);
    }
    __syncthreads();

    const float* __restrict__ fb = feat + (size_t)b * (C * HW);
    float* __restrict__ ob = out + (size_t)r * ELEMS;

    int c = t / NS;
    int s = t - c * NS;
    #pragma unroll 3
    for (int it = 0; it < NS; ++it) {
        const int off = (c << 12) + s_off[s];
        const float4 w = s_w[s];
        const float f00 = fb[off];
        const float f01 = fb[off + 1];
        const float f10 = fb[off + W];
        const float f11 = fb[off + W + 1];
        ob[t + (it << 8)] = f00 * w.x + f01 * w.y + f10 * w.z + f11 * w.w;
        c += 3; s += 13;
        if (s >= NS) { s -= NS; ++c; }
    }
}

extern "C" void kernel_launch(void* const* d_in, const int* in_sizes, int n_in,
                              void* d_out, int out_size, void* d_ws, size_t ws_size,
                              hipStream_t stream) {
    const float* feat = (const float*)d_in[0];
    const float* rois = (const float*)d_in[1];
    float* outp = (float*)d_out;
    const int R = in_sizes[1] / 5;            // 2048
    const int B = in_sizes[0] / (C * HW);     // 4

    const size_t feat_bytes  = (size_t)in_sizes[0] * sizeof(float);
    const size_t lists_bytes = (size_t)(4 * R + 16) * sizeof(int);

    if (B == 4 && ws_size >= feat_bytes + lists_bytes) {
        float* nhwc   = (float*)d_ws;
        int*   counts = (int*)((char*)d_ws + feat_bytes);
        int*   lists  = counts + 16;

        build_lists_kernel<<<1, 256, 0, stream>>>(rois, R, counts, lists);
        dim3 tgrid(HW / 32, C / 32, B);
        dim3 tblk(32, 8);
        nchw_to_nhwc_kernel<<<tgrid, tblk, 0, stream>>>(feat, nhwc);

        const int cap  = (3 * R) / 16;        // per-(xcd,half) slots; covers count<=2*cap
        const int grid = NXCD * 2 * cap;      // 6144 for R=2048
        rod_align_nhwc_kernel<<<grid, 256, 0, stream>>>(nhwc, rois, counts, lists, outp, R);
    } else {
        rod_align_nchw_kernel<<<R, 256, 0, stream>>>(feat, rois, outp);
    }
}

// Round 4
// 60.142 us; speedup vs baseline: 1.1173x; 1.1173x over previous
//
#include <hip/hip_runtime.h>
#include <hip/hip_bf16.h>

namespace {
constexpr int AH = 9, AW = 9, NS = AH * AW;   // 81 samples per ROI
constexpr int C = 256, H = 64, W = 64, HW = H * W;
constexpr int WC = W * C;
constexpr float SCALE = 0.0625f;
constexpr int ELEMS = C * NS;                 // 20736 outputs per ROI
constexpr int CH = 64;                        // channels per chunk
}

// ---------- pass 1: NCHW f32 -> NHWC bf16 into workspace ----------
// per batch: in[c][p] -> out[p][c] (bf16), p = h*64+w
__global__ __launch_bounds__(256)
void nchw_to_nhwc_bf16_kernel(const float* __restrict__ in,
                              ushort* __restrict__ out)
{
    __shared__ float tile[64][33];            // [c within 64][p within 32], padded
    const int b  = blockIdx.z;
    const int p0 = blockIdx.x * 32;
    const int c0 = blockIdx.y * 64;
    const float* src = in + (size_t)b * C * HW;
    ushort*      dst = out + (size_t)b * HW * C;
    const int tx = threadIdx.x;   // 0..31
    const int ty = threadIdx.y;   // 0..7
    #pragma unroll
    for (int k = 0; k < 8; ++k)
        tile[ty + 8 * k][tx] = src[(size_t)(c0 + ty + 8 * k) * HW + p0 + tx];
    __syncthreads();
    #pragma unroll
    for (int k = 0; k < 4; ++k) {
        const int p = ty + 8 * k;             // 0..31
        __hip_bfloat16 lo = __float2bfloat16(tile[2 * tx][p]);
        __hip_bfloat16 hi = __float2bfloat16(tile[2 * tx + 1][p]);
        ushort2 u;
        u.x = *reinterpret_cast<ushort*>(&lo);
        u.y = *reinterpret_cast<ushort*>(&hi);
        *reinterpret_cast<ushort2*>(dst + (size_t)(p0 + p) * C + c0 + 2 * tx) = u;
    }
}

// ---------- pass 2: ROI align from bf16 NHWC ----------
// grid = 2*R; block = one ROI x one half (2 chunks of 64 channels)
__global__ __launch_bounds__(256)
void rod_align_bf16_kernel(const ushort* __restrict__ nhwc,
                           const float* __restrict__ rois,
                           float* __restrict__ out)
{
    __shared__ float4 s_w[NS];
    __shared__ int    s_off[NS];              // (y0*W + x0) * C  (element units)
    __shared__ float  s_buf[NS][CH + 1];

    const int r    = blockIdx.x >> 1;
    const int half = blockIdx.x & 1;
    const int t    = threadIdx.x;
    const int wave = t >> 6;
    const int lane = t & 63;

    const float* roi = rois + r * 5;
    const int   b  = (int)roi[0];
    const float x1 = roi[1] * SCALE;
    const float y1 = roi[2] * SCALE;
    const float x2 = roi[3] * SCALE;
    const float y2 = roi[4] * SCALE;
    const float bin_h = (y2 - y1) * 0.125f;
    const float bin_w = (x2 - x1) * 0.125f;

    if (t < NS) {
        const int i = t / AW;
        const int j = t - i * AW;
        const float Y = y1 + (float)i * bin_h;
        const float X = x1 + (float)j * bin_w;
        const bool valid = (Y >= 0.f) && (Y < (float)H) &&
                           (X >= 0.f) && (X < (float)W);
        const float fy = fminf(fmaxf(floorf(Y), 0.f), (float)(H - 2));
        const float fx = fminf(fmaxf(floorf(X), 0.f), (float)(W - 2));
        const float ly = Y - fy, lx = X - fx;
        const float hy = 1.f - ly, hx = 1.f - lx;
        const float v = valid ? 1.f : 0.f;
        s_off[t] = ((int)fy * W + (int)fx) * C;
        s_w[t] = make_float4(hy * hx * v, hy * lx * v, ly * hx * v, ly * lx * v);
    }
    __syncthreads();

    const ushort* __restrict__ fb = nhwc + (size_t)b * (HW * C);
    float* __restrict__ ob = out + (size_t)r * ELEMS;

    // wave covers 21 samples (wave 3 clamps into 80 — redundant same-value writes)
    const int s_begin = wave * 21;

    for (int ci = 0; ci < 2; ++ci) {
        const int c0 = (half * 2 + ci) * CH;
        const ushort* __restrict__ fc = fb + c0 + lane;

        #pragma unroll
        for (int g = 0; g < 7; ++g) {
            int   ss[3];
            int   off[3];
            ushort a0[3], a1[3], a2[3], a3[3];
            #pragma unroll
            for (int u = 0; u < 3; ++u) {
                int s = s_begin + 3 * g + u;
                ss[u]  = (s < NS) ? s : NS - 1;
                off[u] = s_off[ss[u]];
            }
            #pragma unroll
            for (int u = 0; u < 3; ++u) {     // 12 loads issued together
                a0[u] = fc[off[u]];
                a1[u] = fc[off[u] + C];
                a2[u] = fc[off[u] + WC];
                a3[u] = fc[off[u] + WC + C];
            }
            #pragma unroll
            for (int u = 0; u < 3; ++u) {
                const float4 w4 = s_w[ss[u]];
                const float f00 = __uint_as_float((unsigned)a0[u] << 16);
                const float f01 = __uint_as_float((unsigned)a1[u] << 16);
                const float f10 = __uint_as_float((unsigned)a2[u] << 16);
                const float f11 = __uint_as_float((unsigned)a3[u] << 16);
                s_buf[ss[u]][lane] = f00 * w4.x + f01 * w4.y
                                   + f10 * w4.z + f11 * w4.w;
            }
        }
        __syncthreads();
        // contiguous 5184-float slab: out[r, c0+cc, ss], f = cc*81 + ss
        float* __restrict__ oc = ob + c0 * NS;
        for (int f = t; f < CH * NS; f += 256) {
            const int cc = f / NS;
            const int ssx = f - cc * NS;
            __builtin_nontemporal_store(s_buf[ssx][cc], &oc[f]);
        }
        __syncthreads();
    }
}

// ---------- fallback: direct NCHW f32 (round-1 kernel) ----------
__global__ __launch_bounds__(256, 8)
void rod_align_nchw_kernel(const float* __restrict__ feat,
                           const float* __restrict__ rois,
                           float* __restrict__ out)
{
    __shared__ float4 s_w[NS];
    __shared__ int    s_off[NS];

    const int r = blockIdx.x;
    const int t = threadIdx.x;

    const float* roi = rois + r * 5;
    const int   b  = (int)roi[0];
    const float x1 = roi[1] * SCALE;
    const float y1 = roi[2] * SCALE;
    const float x2 = roi[3] * SCALE;
    const float y2 = roi[4] * SCALE;
    const float bin_h = (y2 - y1) * 0.125f;
    const float bin_w = (x2 - x1) * 0.125f;

    if (t < NS) {
        const int i = t / AW;
        const int j = t - i * AW;
        const float Y = y1 + (float)i * bin_h;
        const float X = x1 + (float)j * bin_w;
        const bool valid = (Y >= 0.f) && (Y < (float)H) &&
                           (X >= 0.f) && (X < (float)W);
        const float fy = fminf(fmaxf(floorf(Y), 0.f), (float)(H - 2));
        const float fx = fminf(fmaxf(floorf(X), 0.f), (float)(W - 2));
        const float ly = Y - fy, lx = X - fx;
        const float hy = 1.f - ly, hx = 1.f - lx;
        const float v = valid ? 1.f : 0.f;
        s_off[t] = (int)fy * W + (int)fx;
        s_w[t] = make_float4(hy * hx * v, hy * lx * v, ly * hx * v, ly * lx * v);
    }
    __syncthreads();

    const float* __restrict__ fb = feat + (size_t)b * (C * HW);
    float* __restrict__ ob = out + (size_t)r * ELEMS;

    int c = t / NS;
    int s = t - c * NS;
    #pragma unroll 3
    for (int it = 0; it < NS; ++it) {
        const int off = (c << 12) + s_off[s];
        const float4 w = s_w[s];
        const float f00 = fb[off];
        const float f01 = fb[off + 1];
        const float f10 = fb[off + W];
        const float f11 = fb[off + W + 1];
        ob[t + (it << 8)] = f00 * w.x + f01 * w.y + f10 * w.z + f11 * w.w;
        c += 3; s += 13;
        if (s >= NS) { s -= NS; ++c; }
    }
}

extern "C" void kernel_launch(void* const* d_in, const int* in_sizes, int n_in,
                              void* d_out, int out_size, void* d_ws, size_t ws_size,
                              hipStream_t stream) {
    const float* feat = (const float*)d_in[0];
    const float* rois = (const float*)d_in[1];
    float* outp = (float*)d_out;
    const int R = in_sizes[1] / 5;            // 2048
    const int B = in_sizes[0] / (C * HW);     // 4

    const size_t nhwc_bytes = (size_t)B * HW * C * sizeof(ushort);

    if (ws_size >= nhwc_bytes) {
        ushort* nhwc = (ushort*)d_ws;
        dim3 tgrid(HW / 32, C / 64, B);
        dim3 tblk(32, 8);
        nchw_to_nhwc_bf16_kernel<<<tgrid, tblk, 0, stream>>>(feat, nhwc);
        rod_align_bf16_kernel<<<2 * R, 256, 0, stream>>>(nhwc, rois, outp);
    } else {
        rod_align_nchw_kernel<<<R, 256, 0, stream>>>(feat, rois, outp);
    }
}

// Round 5
// 57.256 us; speedup vs baseline: 1.1736x; 1.0504x over previous
//
#include <hip/hip_runtime.h>
#include <hip/hip_bf16.h>

namespace {
constexpr int AH = 9, AW = 9, NS = AH * AW;   // 81 samples per ROI
constexpr int C = 256, H = 64, W = 64, HW = H * W;
constexpr float SCALE = 0.0625f;
constexpr int ELEMS = C * NS;                 // 20736 outputs per ROI
constexpr int SPW = 21;                       // samples per wave (4*21 >= 81)
}

__device__ __forceinline__ float bf_lo(unsigned u) { return __uint_as_float(u << 16); }
__device__ __forceinline__ float bf_hi(unsigned u) { return __uint_as_float(u & 0xffff0000u); }

// ---------- pass 1: NCHW f32 -> NHWC bf16 into workspace ----------
__global__ __launch_bounds__(256)
void nchw_to_nhwc_bf16_kernel(const float* __restrict__ in,
                              ushort* __restrict__ out)
{
    __shared__ float tile[64][33];
    const int b  = blockIdx.z;
    const int p0 = blockIdx.x * 32;
    const int c0 = blockIdx.y * 64;
    const float* src = in + (size_t)b * C * HW;
    ushort*      dst = out + (size_t)b * HW * C;
    const int tx = threadIdx.x;   // 0..31
    const int ty = threadIdx.y;   // 0..7
    #pragma unroll
    for (int k = 0; k < 8; ++k)
        tile[ty + 8 * k][tx] = src[(size_t)(c0 + ty + 8 * k) * HW + p0 + tx];
    __syncthreads();
    #pragma unroll
    for (int k = 0; k < 4; ++k) {
        const int p = ty + 8 * k;             // 0..31
        __hip_bfloat16 lo = __float2bfloat16(tile[2 * tx][p]);
        __hip_bfloat16 hi = __float2bfloat16(tile[2 * tx + 1][p]);
        ushort2 u;
        u.x = *reinterpret_cast<ushort*>(&lo);
        u.y = *reinterpret_cast<ushort*>(&hi);
        *reinterpret_cast<ushort2*>(dst + (size_t)(p0 + p) * C + c0 + 2 * tx) = u;
    }
}

// ---------- pass 2: ROI align, one block per ROI ----------
// lane owns 4 channels (uint2 = 4 bf16 per corner); wave w owns samples 21w..
__global__ __launch_bounds__(256)
void rod_align_wide_kernel(const ushort* __restrict__ nhwc,
                           const float* __restrict__ rois,
                           float* __restrict__ out)
{
    __shared__ float4 s_w[NS];
    __shared__ int    s_o[NS];                // (y0*W + x0) * 64  (uint2 units)
    __shared__ float  s_buf[NS][65];

    const int r    = blockIdx.x;
    const int t    = threadIdx.x;
    const int wave = t >> 6;
    const int lane = t & 63;

    const float* roi = rois + r * 5;
    const int   b  = (int)roi[0];
    const float x1 = roi[1] * SCALE;
    const float y1 = roi[2] * SCALE;
    const float x2 = roi[3] * SCALE;
    const float y2 = roi[4] * SCALE;
    const float bin_h = (y2 - y1) * 0.125f;
    const float bin_w = (x2 - x1) * 0.125f;

    if (t < NS) {
        const int i = t / AW;
        const int j = t - i * AW;
        const float Y = y1 + (float)i * bin_h;
        const float X = x1 + (float)j * bin_w;
        const bool valid = (Y >= 0.f) && (Y < (float)H) &&
                           (X >= 0.f) && (X < (float)W);
        const float fy = fminf(fmaxf(floorf(Y), 0.f), (float)(H - 2));
        const float fx = fminf(fmaxf(floorf(X), 0.f), (float)(W - 2));
        const float ly = Y - fy, lx = X - fx;
        const float hy = 1.f - ly, hx = 1.f - lx;
        const float v = valid ? 1.f : 0.f;
        s_o[t] = ((int)fy * W + (int)fx) * (C / 4);
        s_w[t] = make_float4(hy * hx * v, hy * lx * v, ly * hx * v, ly * lx * v);
    }
    __syncthreads();

    const uint2* __restrict__ pl =
        reinterpret_cast<const uint2*>(nhwc + (size_t)b * (HW * C)) + lane;
    float* __restrict__ ob = out + (size_t)r * ELEMS;

    const int s0 = wave * SPW;
    float acc[SPW][4];

    #pragma unroll
    for (int i = 0; i < SPW; ++i) {
        int s = s0 + i; if (s > NS - 1) s = NS - 1;   // wave 3 tail: benign repeats
        const int o = s_o[s];
        const uint2 q00 = pl[o];
        const uint2 q01 = pl[o + 64];          // x+1:   +C/4
        const uint2 q10 = pl[o + 4096];        // y+1:   +W*C/4
        const uint2 q11 = pl[o + 4160];
        const float4 w4 = s_w[s];
        acc[i][0] = bf_lo(q00.x) * w4.x + bf_lo(q01.x) * w4.y
                  + bf_lo(q10.x) * w4.z + bf_lo(q11.x) * w4.w;
        acc[i][1] = bf_hi(q00.x) * w4.x + bf_hi(q01.x) * w4.y
                  + bf_hi(q10.x) * w4.z + bf_hi(q11.x) * w4.w;
        acc[i][2] = bf_lo(q00.y) * w4.x + bf_lo(q01.y) * w4.y
                  + bf_lo(q10.y) * w4.z + bf_lo(q11.y) * w4.w;
        acc[i][3] = bf_hi(q00.y) * w4.x + bf_hi(q01.y) * w4.y
                  + bf_hi(q10.y) * w4.z + bf_hi(q11.y) * w4.w;
    }

    // 4 rounds: channels 64g..64g+63 come from lanes 16g..16g+15 (4 ch each)
    #pragma unroll 1
    for (int g = 0; g < 4; ++g) {
        __syncthreads();                      // s_buf free (prev round consumed)
        if ((lane >> 4) == g) {
            const int kk = (lane & 15) * 4;
            #pragma unroll
            for (int i = 0; i < SPW; ++i) {
                int s = s0 + i; if (s > NS - 1) s = NS - 1;
                s_buf[s][kk]     = acc[i][0];
                s_buf[s][kk + 1] = acc[i][1];
                s_buf[s][kk + 2] = acc[i][2];
                s_buf[s][kk + 3] = acc[i][3];
            }
        }
        __syncthreads();
        float* __restrict__ oc = ob + (g * 64) * NS;   // contiguous 5184-f32 slab
        for (int f = t; f < 64 * NS; f += 256) {
            const int cc  = f / NS;
            const int ssx = f - cc * NS;
            __builtin_nontemporal_store(s_buf[ssx][cc], &oc[f]);
        }
    }
}

// ---------- fallback: direct NCHW f32 ----------
__global__ __launch_bounds__(256, 8)
void rod_align_nchw_kernel(const float* __restrict__ feat,
                           const float* __restrict__ rois,
                           float* __restrict__ out)
{
    __shared__ float4 s_w[NS];
    __shared__ int    s_off[NS];

    const int r = blockIdx.x;
    const int t = threadIdx.x;

    const float* roi = rois + r * 5;
    const int   b  = (int)roi[0];
    const float x1 = roi[1] * SCALE;
    const float y1 = roi[2] * SCALE;
    const float x2 = roi[3] * SCALE;
    const float y2 = roi[4] * SCALE;
    const float bin_h = (y2 - y1) * 0.125f;
    const float bin_w = (x2 - x1) * 0.125f;

    if (t < NS) {
        const int i = t / AW;
        const int j = t - i * AW;
        const float Y = y1 + (float)i * bin_h;
        const float X = x1 + (float)j * bin_w;
        const bool valid = (Y >= 0.f) && (Y < (float)H) &&
                           (X >= 0.f) && (X < (float)W);
        const float fy = fminf(fmaxf(floorf(Y), 0.f), (float)(H - 2));
        const float fx = fminf(fmaxf(floorf(X), 0.f), (float)(W - 2));
        const float ly = Y - fy, lx = X - fx;
        const float hy = 1.f - ly, hx = 1.f - lx;
        const float v = valid ? 1.f : 0.f;
        s_off[t] = (int)fy * W + (int)fx;
        s_w[t] = make_float4(hy * hx * v, hy * lx * v, ly * hx * v, ly * lx * v);
    }
    __syncthreads();

    const float* __restrict__ fb = feat + (size_t)b * (C * HW);
    float* __restrict__ ob = out + (size_t)r * ELEMS;

    int c = t / NS;
    int s = t - c * NS;
    #pragma unroll 3
    for (int it = 0; it < NS; ++it) {
        const int off = (c << 12) + s_off[s];
        const float4 w = s_w[s];
        const float f00 = fb[off];
        const float f01 = fb[off + 1];
        const float f10 = fb[off + W];
        const float f11 = fb[off + W + 1];
        ob[t + (it << 8)] = f00 * w.x + f01 * w.y + f10 * w.z + f11 * w.w;
        c += 3; s += 13;
        if (s >= NS) { s -= NS; ++c; }
    }
}

extern "C" void kernel_launch(void* const* d_in, const int* in_sizes, int n_in,
                              void* d_out, int out_size, void* d_ws, size_t ws_size,
                              hipStream_t stream) {
    const float* feat = (const float*)d_in[0];
    const float* rois = (const float*)d_in[1];
    float* outp = (float*)d_out;
    const int R = in_sizes[1] / 5;            // 2048
    const int B = in_sizes[0] / (C * HW);     // 4

    const size_t nhwc_bytes = (size_t)B * HW * C * sizeof(ushort);

    if (ws_size >= nhwc_bytes) {
        ushort* nhwc = (ushort*)d_ws;
        dim3 tgrid(HW / 32, C / 64, B);
        dim3 tblk(32, 8);
        nchw_to_nhwc_bf16_kernel<<<tgrid, tblk, 0, stream>>>(feat, nhwc);
        rod_align_wide_kernel<<<R, 256, 0, stream>>>(nhwc, rois, outp);
    } else {
        rod_align_nchw_kernel<<<R, 256, 0, stream>>>(feat, rois, outp);
    }
}

// Round 6
// 50.603 us; speedup vs baseline: 1.3280x; 1.1315x over previous
//
#include <hip/hip_runtime.h>
#include <hip/hip_bf16.h>

namespace {
constexpr int AH = 9, AW = 9, NS = AH * AW;   // 81 samples per ROI
constexpr int C = 256, H = 64, W = 64, HW = H * W;
constexpr float SCALE = 0.0625f;
constexpr int ELEMS = C * NS;                 // 20736 outputs per ROI
constexpr int SPW = 21;                       // samples per wave (4*21 >= 81)
}

__device__ __forceinline__ float bf_lo(unsigned u) { return __uint_as_float(u << 16); }
__device__ __forceinline__ float bf_hi(unsigned u) { return __uint_as_float(u & 0xffff0000u); }

// ---------- pass 1: NCHW f32 -> NHWC bf16 into workspace ----------
__global__ __launch_bounds__(256)
void nchw_to_nhwc_bf16_kernel(const float* __restrict__ in,
                              ushort* __restrict__ out)
{
    __shared__ float tile[64][33];
    const int b  = blockIdx.z;
    const int p0 = blockIdx.x * 32;
    const int c0 = blockIdx.y * 64;
    const float* src = in + (size_t)b * C * HW;
    ushort*      dst = out + (size_t)b * HW * C;
    const int tx = threadIdx.x;   // 0..31
    const int ty = threadIdx.y;   // 0..7
    #pragma unroll
    for (int k = 0; k < 8; ++k)
        tile[ty + 8 * k][tx] = src[(size_t)(c0 + ty + 8 * k) * HW + p0 + tx];
    __syncthreads();
    #pragma unroll
    for (int k = 0; k < 4; ++k) {
        const int p = ty + 8 * k;             // 0..31
        __hip_bfloat16 lo = __float2bfloat16(tile[2 * tx][p]);
        __hip_bfloat16 hi = __float2bfloat16(tile[2 * tx + 1][p]);
        ushort2 u;
        u.x = *reinterpret_cast<ushort*>(&lo);
        u.y = *reinterpret_cast<ushort*>(&hi);
        *reinterpret_cast<ushort2*>(dst + (size_t)(p0 + p) * C + c0 + 2 * tx) = u;
    }
}

// ---------- pass 2: ROI align, one block per (ROI, 128-channel half) ----------
// lane owns 2 channels (1 dword = 2 bf16 per corner); wave w owns samples 21w..
__global__ __launch_bounds__(256, 5)
void rod_align_half_kernel(const ushort* __restrict__ nhwc,
                           const float* __restrict__ rois,
                           float* __restrict__ out)
{
    __shared__ float4 s_w[NS];
    __shared__ int    s_o[NS];                // (y0*W + x0) * C/2  (dword units)
    __shared__ float  s_buf[NS][65];

    const int r    = blockIdx.x >> 1;
    const int half = blockIdx.x & 1;
    const int t    = threadIdx.x;
    const int wave = t >> 6;
    const int lane = t & 63;

    const float* roi = rois + r * 5;
    const int   b  = (int)roi[0];
    const float x1 = roi[1] * SCALE;
    const float y1 = roi[2] * SCALE;
    const float x2 = roi[3] * SCALE;
    const float y2 = roi[4] * SCALE;
    const float bin_h = (y2 - y1) * 0.125f;
    const float bin_w = (x2 - x1) * 0.125f;

    if (t < NS) {
        const int i = t / AW;
        const int j = t - i * AW;
        const float Y = y1 + (float)i * bin_h;
        const float X = x1 + (float)j * bin_w;
        const bool valid = (Y >= 0.f) && (Y < (float)H) &&
                           (X >= 0.f) && (X < (float)W);
        const float fy = fminf(fmaxf(floorf(Y), 0.f), (float)(H - 2));
        const float fx = fminf(fmaxf(floorf(X), 0.f), (float)(W - 2));
        const float ly = Y - fy, lx = X - fx;
        const float hy = 1.f - ly, hx = 1.f - lx;
        const float v = valid ? 1.f : 0.f;
        s_o[t] = ((int)fy * W + (int)fx) * (C / 2);
        s_w[t] = make_float4(hy * hx * v, hy * lx * v, ly * hx * v, ly * lx * v);
    }
    __syncthreads();

    // dword view: 2 bf16 channels per lane; half selects channels 128*half..+127
    const unsigned* __restrict__ pd =
        reinterpret_cast<const unsigned*>(nhwc + (size_t)b * (HW * C)) + half * 64 + lane;
    float* __restrict__ ob = out + (size_t)r * ELEMS;

    const int s0 = wave * SPW;
    float acc[SPW][2];

    #pragma unroll
    for (int i = 0; i < SPW; ++i) {
        int s = s0 + i; if (s > NS - 1) s = NS - 1;   // wave-3 tail: benign repeats
        const int o = s_o[s];
        const unsigned q00 = pd[o];
        const unsigned q01 = pd[o + 128];      // x+1:  +C/2 dwords
        const unsigned q10 = pd[o + 8192];     // y+1:  +W*C/2 dwords
        const unsigned q11 = pd[o + 8320];
        const float4 w4 = s_w[s];
        acc[i][0] = bf_lo(q00) * w4.x + bf_lo(q01) * w4.y
                  + bf_lo(q10) * w4.z + bf_lo(q11) * w4.w;
        acc[i][1] = bf_hi(q00) * w4.x + bf_hi(q01) * w4.y
                  + bf_hi(q10) * w4.z + bf_hi(q11) * w4.w;
    }

    // 2 rounds: channels 64g..64g+63 (of this half) come from lanes 32g..32g+31
    #pragma unroll 1
    for (int g = 0; g < 2; ++g) {
        __syncthreads();                      // s_buf free (prev round consumed)
        if ((lane >> 5) == g) {
            const int kk = (lane & 31) * 2;
            #pragma unroll
            for (int i = 0; i < SPW; ++i) {
                int s = s0 + i; if (s > NS - 1) s = NS - 1;
                s_buf[s][kk]     = acc[i][0];
                s_buf[s][kk + 1] = acc[i][1];
            }
        }
        __syncthreads();
        // contiguous 5184-f32 slab: out[r, 128*half + 64g + cc, ss]
        float* __restrict__ oc = ob + (half * 128 + g * 64) * NS;
        for (int f = t; f < 64 * NS; f += 256) {
            const int cc  = f / NS;
            const int ssx = f - cc * NS;
            __builtin_nontemporal_store(s_buf[ssx][cc], &oc[f]);
        }
    }
}

// ---------- fallback: direct NCHW f32 ----------
__global__ __launch_bounds__(256, 8)
void rod_align_nchw_kernel(const float* __restrict__ feat,
                           const float* __restrict__ rois,
                           float* __restrict__ out)
{
    __shared__ float4 s_w[NS];
    __shared__ int    s_off[NS];

    const int r = blockIdx.x;
    const int t = threadIdx.x;

    const float* roi = rois + r * 5;
    const int   b  = (int)roi[0];
    const float x1 = roi[1] * SCALE;
    const float y1 = roi[2] * SCALE;
    const float x2 = roi[3] * SCALE;
    const float y2 = roi[4] * SCALE;
    const float bin_h = (y2 - y1) * 0.125f;
    const float bin_w = (x2 - x1) * 0.125f;

    if (t < NS) {
        const int i = t / AW;
        const int j = t - i * AW;
        const float Y = y1 + (float)i * bin_h;
        const float X = x1 + (float)j * bin_w;
        const bool valid = (Y >= 0.f) && (Y < (float)H) &&
                           (X >= 0.f) && (X < (float)W);
        const float fy = fminf(fmaxf(floorf(Y), 0.f), (float)(H - 2));
        const float fx = fminf(fmaxf(floorf(X), 0.f), (float)(W - 2));
        const float ly = Y - fy, lx = X - fx;
        const float hy = 1.f - ly, hx = 1.f - lx;
        const float v = valid ? 1.f : 0.f;
        s_off[t] = (int)fy * W + (int)fx;
        s_w[t] = make_float4(hy * hx * v, hy * lx * v, ly * hx * v, ly * lx * v);
    }
    __syncthreads();

    const float* __restrict__ fb = feat + (size_t)b * (C * HW);
    float* __restrict__ ob = out + (size_t)r * ELEMS;

    int c = t / NS;
    int s = t - c * NS;
    #pragma unroll 3
    for (int it = 0; it < NS; ++it) {
        const int off = (c << 12) + s_off[s];
        const float4 w = s_w[s];
        const float f00 = fb[off];
        const float f01 = fb[off + 1];
        const float f10 = fb[off + W];
        const float f11 = fb[off + W + 1];
        ob[t + (it << 8)] = f00 * w.x + f01 * w.y + f10 * w.z + f11 * w.w;
        c += 3; s += 13;
        if (s >= NS) { s -= NS; ++c; }
    }
}

extern "C" void kernel_launch(void* const* d_in, const int* in_sizes, int n_in,
                              void* d_out, int out_size, void* d_ws, size_t ws_size,
                              hipStream_t stream) {
    const float* feat = (const float*)d_in[0];
    const float* rois = (const float*)d_in[1];
    float* outp = (float*)d_out;
    const int R = in_sizes[1] / 5;            // 2048
    const int B = in_sizes[0] / (C * HW);     // 4

    const size_t nhwc_bytes = (size_t)B * HW * C * sizeof(ushort);

    if (ws_size >= nhwc_bytes) {
        ushort* nhwc = (ushort*)d_ws;
        dim3 tgrid(HW / 32, C / 64, B);
        dim3 tblk(32, 8);
        nchw_to_nhwc_bf16_kernel<<<tgrid, tblk, 0, stream>>>(feat, nhwc);
        rod_align_half_kernel<<<2 * R, 256, 0, stream>>>(nhwc, rois, outp);
    } else {
        rod_align_nchw_kernel<<<R, 256, 0, stream>>>(feat, rois, outp);
    }
}